// Round 15
// baseline (438.892 us; speedup 1.0000x reference)
//
#include <hip/hip_runtime.h>

#define NN 100000
#define NE 1600000
#define SCAN_CH 1024
#define GEMM_GRID 1563            // ceil(NN/64)
#define SCAT_BLOCKS 625           // persistent scatter blocks (10 edges/thread)
#define SCAT_STRIDE (SCAT_BLOCKS * 256)
#define SG_GRID (SCAT_BLOCKS + GEMM_GRID)
#define WH_GRID (16 + SCAT_BLOCKS)
#define AGG_GRID 50000            // 4 heads x 12500 node-blocks (8 nodes/block)

typedef short bf16x8 __attribute__((ext_vector_type(8)));
typedef float f32x4 __attribute__((ext_vector_type(4)));
typedef unsigned int u32;
typedef u32 u32x4 __attribute__((ext_vector_type(4)));
typedef unsigned short u16;

__device__ inline u32 bf16r(float x) {  // RTNE bf16, returns low-16 bits
    u32 u = __float_as_uint(x);
    return (u + 0x7FFFu + ((u >> 16) & 1u)) >> 16;
}

// ---------------- split-bf16 helpers ----------------
__device__ inline void split_pack8(const float a[8], u32 hh[4], u32 ll[4]) {
#pragma unroll
    for (int j = 0; j < 4; ++j) {
        u32 u0 = __float_as_uint(a[2 * j]);
        u32 u1 = __float_as_uint(a[2 * j + 1]);
        float l0 = a[2 * j] - __uint_as_float(u0 & 0xFFFF0000u);
        float l1 = a[2 * j + 1] - __uint_as_float(u1 & 0xFFFF0000u);
        hh[j] = (u0 >> 16) | (u1 & 0xFFFF0000u);
        ll[j] = (__float_as_uint(l0) >> 16) | (__float_as_uint(l1) & 0xFFFF0000u);
    }
}

__device__ inline void wpack_body(int idx, const float* __restrict__ W,
                                  bf16x8* __restrict__ wpH, bf16x8* __restrict__ wpL) {
    if (idx >= 2048) return;
    int lane = idx & 63, tile = idx >> 6;
    int kc = tile >> 3, ct = tile & 7;
    int col = lane & 15, kq = lane >> 4;
    int kbase = kc * 32 + kq * 8;
    float a[8];
#pragma unroll
    for (int i = 0; i < 8; ++i)
        a[i] = W[(size_t)(kbase + i) * 128 + ct * 16 + col];
    u32 hh[4], ll[4];
    split_pack8(a, hh, ll);
    wpH[tile * 64 + lane] = __builtin_bit_cast(bf16x8, (u32x4){hh[0], hh[1], hh[2], hh[3]});
    wpL[tile * 64 + lane] = __builtin_bit_cast(bf16x8, (u32x4){ll[0], ll[1], ll[2], ll[3]});
}

// ---------------- fused: wpack(W1) | wpack(W2) | persistent hist+occ --------
__global__ __launch_bounds__(256) void k_wh(
    const float* __restrict__ W1, bf16x8* __restrict__ wpH1, bf16x8* __restrict__ wpL1,
    const float* __restrict__ W2, bf16x8* __restrict__ wpH2, bf16x8* __restrict__ wpL2,
    const int* __restrict__ dst, int* __restrict__ counts, int* __restrict__ occ) {
    int b = blockIdx.x;
    if (b < 8) {
        wpack_body(b * 256 + threadIdx.x, W1, wpH1, wpL1);
    } else if (b < 16) {
        wpack_body((b - 8) * 256 + threadIdx.x, W2, wpH2, wpL2);
    } else {
        int tid = (b - 16) * 256 + threadIdx.x;
#pragma unroll
        for (int k = 0; k < 10; ++k) {
            int e = tid + k * SCAT_STRIDE;
            occ[e] = atomicAdd(&counts[dst[e]], 1);
        }
    }
}

// ---------------- scans (scan2 fused into scan3) ----------------
__global__ __launch_bounds__(256) void k_scan1(const int* __restrict__ counts,
                                               int* __restrict__ csum) {
    __shared__ int sd[256];
    int t = threadIdx.x;
    int base = blockIdx.x * SCAN_CH + t * 4;
    int s = 0;
#pragma unroll
    for (int u = 0; u < 4; ++u) {
        int i = base + u;
        if (i < NN) s += counts[i];
    }
    sd[t] = s;
    __syncthreads();
    for (int off = 128; off > 0; off >>= 1) {
        if (t < off) sd[t] += sd[t + off];
        __syncthreads();
    }
    if (t == 0) csum[blockIdx.x] = sd[0];
}

__global__ __launch_bounds__(256) void k_scan3(const int* __restrict__ counts,
                                               const int* __restrict__ csum,
                                               int* __restrict__ row_ptr) {
    __shared__ int sd[256];
    __shared__ int sbase;
    int t = threadIdx.x, b = blockIdx.x;
    if (t < 64) {
        int acc = 0;
        for (int i = t; i < b; i += 64) acc += csum[i];
#pragma unroll
        for (int m = 1; m < 64; m <<= 1) acc += __shfl_xor(acc, m);
        if (t == 0) sbase = acc;
    }
    int base = b * SCAN_CH + t * 4;
    int v[4];
    int s = 0;
#pragma unroll
    for (int u = 0; u < 4; ++u) {
        int i = base + u;
        v[u] = (i < NN) ? counts[i] : 0;
        s += v[u];
    }
    sd[t] = s;
    __syncthreads();
    for (int off = 1; off < 256; off <<= 1) {
        int x = (t >= off) ? sd[t - off] : 0;
        __syncthreads();
        sd[t] += x;
        __syncthreads();
    }
    int excl = (t == 0) ? 0 : sd[t - 1];
    int run = sbase + excl;
#pragma unroll
    for (int u = 0; u < 4; ++u) {
        int i = base + u;
        if (i < NN) row_ptr[i] = run;
        run += v[u];
    }
    if (b == 0 && t == 0) row_ptr[NN] = NE;
}

// shared GEMM epilogue: h (bf16, HEAD-MAJOR [4][NN][32]) + attention logits
__device__ inline void gemm_epilogue(f32x4 acc[8], int row0, int w, int col, int kq,
                                     const float* __restrict__ atts,
                                     const float* __restrict__ attd,
                                     u16* __restrict__ hb,
                                     float* __restrict__ a_src,
                                     float* __restrict__ a_dst) {
    float as0[4], as1[4], ad0[4], ad1[4];
#pragma unroll
    for (int q = 0; q < 4; ++q) {
        as0[q] = atts[q * 32 + col];
        as1[q] = atts[q * 32 + 16 + col];
        ad0[q] = attd[q * 32 + col];
        ad1[q] = attd[q * 32 + 16 + col];
    }
#pragma unroll
    for (int r = 0; r < 4; ++r) {
        int node = row0 + w * 16 + kq * 4 + r;
        float ps[4], pd[4];
#pragma unroll
        for (int q = 0; q < 4; ++q) {
            float d0 = acc[2 * q][r], d1 = acc[2 * q + 1][r];
            ps[q] = d0 * as0[q] + d1 * as1[q];
            pd[q] = d0 * ad0[q] + d1 * ad1[q];
        }
#pragma unroll
        for (int off = 1; off < 16; off <<= 1) {
#pragma unroll
            for (int q = 0; q < 4; ++q) {
                ps[q] += __shfl_xor(ps[q], off);
                pd[q] += __shfl_xor(pd[q], off);
            }
        }
        if (node < NN) {
#pragma unroll
            for (int ct = 0; ct < 8; ++ct)
                hb[((size_t)(ct >> 1) * NN + node) * 32 + (ct & 1) * 16 + col] =
                    (u16)bf16r(acc[ct][r]);
            if (col < 4) {
                float vs = col == 0 ? ps[0] : col == 1 ? ps[1] : col == 2 ? ps[2] : ps[3];
                float vd = col == 0 ? pd[0] : col == 1 ? pd[1] : col == 2 ? pd[2] : pd[3];
                a_src[node * 4 + col] = vs;
                a_dst[node * 4 + col] = vd;
            }
        }
    }
}

// ---------------- fused: persistent scatter | gemm1 -------------------------
__global__ __launch_bounds__(256) void k_sg(
    const float* __restrict__ x,
    const bf16x8* __restrict__ wpH, const bf16x8* __restrict__ wpL,
    const float* __restrict__ atts, const float* __restrict__ attd,
    u16* __restrict__ hb, float* __restrict__ a_src, float* __restrict__ a_dst,
    const int* __restrict__ src, const int* __restrict__ dst,
    const int* __restrict__ occ, const int* __restrict__ row_ptr,
    int* __restrict__ src_sorted) {
    const int idx = blockIdx.x;
    if (idx < SCAT_BLOCKS) {
        int tid = idx * 256 + threadIdx.x;
#pragma unroll
        for (int k = 0; k < 10; ++k) {
            int e = tid + k * SCAT_STRIDE;
            int d = dst[e];
            src_sorted[row_ptr[d] + occ[e]] = src[e];
        }
        return;
    }
    const int t = threadIdx.x;
    const int row0 = (idx - SCAT_BLOCKS) * 64;
    const int lane = t & 63;
    const int w = t >> 6;
    const int col = lane & 15, kq = lane >> 4;
    int node_a = row0 + w * 16 + col;
    if (node_a > NN - 1) node_a = NN - 1;
    const float* xrow = x + (size_t)node_a * 128 + kq * 8;
    float a[32];
#pragma unroll
    for (int kc = 0; kc < 4; ++kc) {
        *(float4*)&a[kc * 8 + 0] = *(const float4*)(xrow + kc * 32);
        *(float4*)&a[kc * 8 + 4] = *(const float4*)(xrow + kc * 32 + 4);
    }
    f32x4 acc[8];
#pragma unroll
    for (int ct = 0; ct < 8; ++ct) acc[ct] = (f32x4){0.f, 0.f, 0.f, 0.f};
#pragma unroll
    for (int kc = 0; kc < 4; ++kc) {
        u32 hh[4], ll[4];
        split_pack8(&a[kc * 8], hh, ll);
        bf16x8 ah = __builtin_bit_cast(bf16x8, (u32x4){hh[0], hh[1], hh[2], hh[3]});
        bf16x8 al = __builtin_bit_cast(bf16x8, (u32x4){ll[0], ll[1], ll[2], ll[3]});
#pragma unroll
        for (int ct = 0; ct < 8; ++ct) {
            bf16x8 bh = wpH[(kc * 8 + ct) * 64 + lane];
            bf16x8 bl = wpL[(kc * 8 + ct) * 64 + lane];
            acc[ct] = __builtin_amdgcn_mfma_f32_16x16x32_bf16(ah, bh, acc[ct], 0, 0, 0);
            acc[ct] = __builtin_amdgcn_mfma_f32_16x16x32_bf16(al, bh, acc[ct], 0, 0, 0);
            acc[ct] = __builtin_amdgcn_mfma_f32_16x16x32_bf16(ah, bl, acc[ct], 0, 0, 0);
        }
    }
    gemm_epilogue(acc, row0, w, col, kq, atts, attd, hb, a_src, a_dst);
}

// ---------------- GEMM layer 2: bf16 input (exact A), LDS-free --------------
__global__ __launch_bounds__(256) void k_gemm2(
    const u32* __restrict__ xb,   // [NN][64] bf16 pairs (ch 2j low, 2j+1 high)
    const bf16x8* __restrict__ wpH, const bf16x8* __restrict__ wpL,
    const float* __restrict__ atts, const float* __restrict__ attd,
    u16* __restrict__ hb, float* __restrict__ a_src, float* __restrict__ a_dst) {
    const int t = threadIdx.x;
    const int row0 = blockIdx.x * 64;
    const int lane = t & 63;
    const int w = t >> 6;
    const int col = lane & 15, kq = lane >> 4;
    int node_a = row0 + w * 16 + col;
    if (node_a > NN - 1) node_a = NN - 1;
    const u32* xrow = xb + (size_t)node_a * 64 + kq * 4;
    int4 aw[4];
#pragma unroll
    for (int kc = 0; kc < 4; ++kc) aw[kc] = *(const int4*)(xrow + kc * 16);
    f32x4 acc[8];
#pragma unroll
    for (int ct = 0; ct < 8; ++ct) acc[ct] = (f32x4){0.f, 0.f, 0.f, 0.f};
#pragma unroll
    for (int kc = 0; kc < 4; ++kc) {
        bf16x8 a = __builtin_bit_cast(bf16x8, aw[kc]);
#pragma unroll
        for (int ct = 0; ct < 8; ++ct) {
            bf16x8 bh = wpH[(kc * 8 + ct) * 64 + lane];
            bf16x8 bl = wpL[(kc * 8 + ct) * 64 + lane];
            acc[ct] = __builtin_amdgcn_mfma_f32_16x16x32_bf16(a, bh, acc[ct], 0, 0, 0);
            acc[ct] = __builtin_amdgcn_mfma_f32_16x16x32_bf16(a, bl, acc[ct], 0, 0, 0);
        }
    }
    gemm_epilogue(acc, row0, w, col, kq, atts, attd, hb, a_src, a_dst);
}

// ---------------- aggregation: head-sliced (64 B lines), XCD-affine ---------
// Head g = blockIdx&3 -> XCDs {g, g+4} (round-robin dispatch). Gather of edge
// e for head g = ONE full 64 B line from hg[sv]. Lane = es*16+cp: 16 lanes
// share an edge (cp = channel pair), es = edge slot; 4 edges in flight x4
// unroll = 16/chunk. Logits computed in-lane (no shuffles in loop); den/acc
// reduced over es bits once per node.
__global__ __launch_bounds__(256) void k_agg(
    const u32* __restrict__ hbs,   // [4][NN][16] u32 head-major bf16 pairs
    const float* __restrict__ a_src, const float* __restrict__ a_dst,
    const int* __restrict__ row_ptr, const int* __restrict__ src_sorted,
    const float* __restrict__ bias,
    u32* __restrict__ x1b, float* __restrict__ outp, int layer) {
    const int lane = threadIdx.x & 63;
    const int wv = threadIdx.x >> 6;
    const int g = blockIdx.x & 3;
    const int nb = blockIdx.x >> 2;
    const int cp = lane & 15;
    const int es = lane >> 4;
    const u32* __restrict__ hg = hbs + (size_t)g * NN * 16;
    const float bv0 = bias[g * 32 + cp * 2];
    const float bv1 = bias[g * 32 + cp * 2 + 1];
#pragma unroll
    for (int ni = 0; ni < 2; ++ni) {
        const int node = nb * 8 + wv * 2 + ni;
        const int e0 = row_ptr[node], e1 = row_ptr[node + 1];
        const int emax = e1 - 1;
        const float advh = a_dst[node * 4 + g];
        float den = 0.f, a0 = 0.f, a1 = 0.f;
        for (int ec = e0; ec < e1; ec += 16) {
            int e_[4];
            bool v_[4];
#pragma unroll
            for (int k = 0; k < 4; ++k) {
                int e = ec + k * 4 + es;
                v_[k] = e <= emax;
                e_[k] = v_[k] ? e : emax;
            }
            int sv_[4];
#pragma unroll
            for (int k = 0; k < 4; ++k) sv_[k] = src_sorted[e_[k]];
            u32 w_[4];
#pragma unroll
            for (int k = 0; k < 4; ++k) w_[k] = hg[(size_t)sv_[k] * 16 + cp];
            float av_[4];
#pragma unroll
            for (int k = 0; k < 4; ++k) av_[k] = a_src[sv_[k] * 4 + g];
#pragma unroll
            for (int k = 0; k < 4; ++k) {
                float lk = av_[k] + advh;
                lk = lk > 0.f ? lk : 0.2f * lk;
                float ex = v_[k] ? __expf(lk - 8.f) : 0.f;
                den += ex;
                a0 = fmaf(ex, __uint_as_float(w_[k] << 16), a0);
                a1 = fmaf(ex, __uint_as_float(w_[k] & 0xFFFF0000u), a1);
            }
        }
        // reduce over es (lane bits 4,5); cp lanes keep their channel pair
        den += __shfl_xor(den, 16);
        den += __shfl_xor(den, 32);
        a0 += __shfl_xor(a0, 16);
        a0 += __shfl_xor(a0, 32);
        a1 += __shfl_xor(a1, 16);
        a1 += __shfl_xor(a1, 32);
        float inv = den > 0.f ? 1.f / den : 0.f;
        float r0 = fmaxf(fmaf(a0, inv, bv0), 0.f);
        float r1 = fmaxf(fmaf(a1, inv, bv1), 0.f);
        if (es == 0) {
            if (layer == 1) {
                x1b[node * 64 + g * 16 + cp] = bf16r(r0) | (bf16r(r1) << 16);
            } else {
                u32 w1 = x1b[node * 64 + g * 16 + cp];
                float4 o;
                o.x = __uint_as_float(w1 << 16);          // x1[2c]
                o.y = r0;                                  // x2[2c]
                o.z = __uint_as_float(w1 & 0xFFFF0000u);  // x1[2c+1]
                o.w = r1;                                  // x2[2c+1]
                *(float4*)(outp + (size_t)node * 256 + (g * 16 + cp) * 4) = o;
            }
        }
    }
}

// ---------------- launch ----------------

extern "C" void kernel_launch(void* const* d_in, const int* in_sizes, int n_in,
                              void* d_out, int out_size, void* d_ws, size_t ws_size,
                              hipStream_t stream) {
    const float* x   = (const float*)d_in[0];
    const int*   ei  = (const int*)d_in[1];
    const float* W1  = (const float*)d_in[2];
    const float* as1 = (const float*)d_in[3];
    const float* ad1 = (const float*)d_in[4];
    const float* b1  = (const float*)d_in[5];
    const float* W2  = (const float*)d_in[6];
    const float* as2 = (const float*)d_in[7];
    const float* ad2 = (const float*)d_in[8];
    const float* b2  = (const float*)d_in[9];
    float* out = (float*)d_out;
    const int* src = ei;
    const int* dst = ei + NE;

    char* w = (char*)d_ws;
    size_t off = 0;
    auto alloc = [&](size_t bytes) -> void* {
        void* p = w + off;
        off = (off + bytes + 255) & ~((size_t)255);
        return p;
    };
    u16* hb         = (u16*)alloc((size_t)NN * 128 * 2);   // h bf16, [4][NN][32]
    u32* x1b        = (u32*)alloc((size_t)NN * 64 * 4);    // x1 as bf16 pairs
    float* a_src    = (float*)alloc((size_t)NN * 4 * 4);
    float* a_dst    = (float*)alloc((size_t)NN * 4 * 4);
    int* counts     = (int*)alloc((size_t)NN * 4);
    int* row_ptr    = (int*)alloc((size_t)(NN + 1) * 4);
    int* csum       = (int*)alloc(4096);
    int* occ        = (int*)alloc((size_t)NE * 4);
    int* src_sorted = (int*)alloc((size_t)NE * 4);
    bf16x8* wpH1    = (bf16x8*)alloc(2048 * 16);
    bf16x8* wpL1    = (bf16x8*)alloc(2048 * 16);
    bf16x8* wpH2    = (bf16x8*)alloc(2048 * 16);
    bf16x8* wpL2    = (bf16x8*)alloc(2048 * 16);

    const int nch = (NN + SCAN_CH - 1) / SCAN_CH;  // 98

    (void)hipMemsetAsync(counts, 0, (size_t)NN * 4, stream);
    k_wh<<<WH_GRID, 256, 0, stream>>>(W1, wpH1, wpL1, W2, wpH2, wpL2,
                                      dst, counts, occ);
    k_scan1<<<nch, 256, 0, stream>>>(counts, csum);
    k_scan3<<<nch, 256, 0, stream>>>(counts, csum, row_ptr);
    k_sg<<<SG_GRID, 256, 0, stream>>>(x, wpH1, wpL1, as1, ad1, hb, a_src, a_dst,
                                      src, dst, occ, row_ptr, src_sorted);

    k_agg<<<AGG_GRID, 256, 0, stream>>>((const u32*)hb, a_src, a_dst, row_ptr,
                                        src_sorted, b1, x1b, out, 1);
    k_gemm2<<<(NN + 63) / 64, 256, 0, stream>>>(x1b, wpH2, wpL2, as2, ad2,
                                                hb, a_src, a_dst);
    k_agg<<<AGG_GRID, 256, 0, stream>>>((const u32*)hb, a_src, a_dst, row_ptr,
                                        src_sorted, b2, x1b, out, 2);
}

// Round 16
// 317.296 us; speedup vs baseline: 1.3832x; 1.3832x over previous
//
#include <hip/hip_runtime.h>

#define NN 100000
#define NE 1600000
#define SCAN_CH 1024
#define GEMM_GRID 1563            // ceil(NN/64)
#define SCAT_BLOCKS 625           // persistent scatter blocks (10 edges/thread)
#define SCAT_STRIDE (SCAT_BLOCKS * 256)
#define SG_GRID (SCAT_BLOCKS + GEMM_GRID)
#define WH_GRID (16 + SCAT_BLOCKS)
#define AGG_GRID 12500            // 256 thr, 4 waves, 2 nodes/wave -> 8 nodes/block

typedef short bf16x8 __attribute__((ext_vector_type(8)));
typedef float f32x4 __attribute__((ext_vector_type(4)));
typedef unsigned int u32;
typedef u32 u32x4 __attribute__((ext_vector_type(4)));
typedef unsigned short u16;

__device__ inline u32 bf16r(float x) {  // RTNE bf16, returns low-16 bits
    u32 u = __float_as_uint(x);
    return (u + 0x7FFFu + ((u >> 16) & 1u)) >> 16;
}

// ---------------- split-bf16 helpers ----------------
__device__ inline void split_pack8(const float a[8], u32 hh[4], u32 ll[4]) {
#pragma unroll
    for (int j = 0; j < 4; ++j) {
        u32 u0 = __float_as_uint(a[2 * j]);
        u32 u1 = __float_as_uint(a[2 * j + 1]);
        float l0 = a[2 * j] - __uint_as_float(u0 & 0xFFFF0000u);
        float l1 = a[2 * j + 1] - __uint_as_float(u1 & 0xFFFF0000u);
        hh[j] = (u0 >> 16) | (u1 & 0xFFFF0000u);
        ll[j] = (__float_as_uint(l0) >> 16) | (__float_as_uint(l1) & 0xFFFF0000u);
    }
}

__device__ inline void wpack_body(int idx, const float* __restrict__ W,
                                  bf16x8* __restrict__ wpH, bf16x8* __restrict__ wpL) {
    if (idx >= 2048) return;
    int lane = idx & 63, tile = idx >> 6;
    int kc = tile >> 3, ct = tile & 7;
    int col = lane & 15, kq = lane >> 4;
    int kbase = kc * 32 + kq * 8;
    float a[8];
#pragma unroll
    for (int i = 0; i < 8; ++i)
        a[i] = W[(size_t)(kbase + i) * 128 + ct * 16 + col];
    u32 hh[4], ll[4];
    split_pack8(a, hh, ll);
    wpH[tile * 64 + lane] = __builtin_bit_cast(bf16x8, (u32x4){hh[0], hh[1], hh[2], hh[3]});
    wpL[tile * 64 + lane] = __builtin_bit_cast(bf16x8, (u32x4){ll[0], ll[1], ll[2], ll[3]});
}

// ---------------- fused: wpack(W1) | wpack(W2) | persistent hist+occ --------
__global__ __launch_bounds__(256) void k_wh(
    const float* __restrict__ W1, bf16x8* __restrict__ wpH1, bf16x8* __restrict__ wpL1,
    const float* __restrict__ W2, bf16x8* __restrict__ wpH2, bf16x8* __restrict__ wpL2,
    const int* __restrict__ dst, int* __restrict__ counts, int* __restrict__ occ) {
    int b = blockIdx.x;
    if (b < 8) {
        wpack_body(b * 256 + threadIdx.x, W1, wpH1, wpL1);
    } else if (b < 16) {
        wpack_body((b - 8) * 256 + threadIdx.x, W2, wpH2, wpL2);
    } else {
        int tid = (b - 16) * 256 + threadIdx.x;
#pragma unroll
        for (int k = 0; k < 10; ++k) {
            int e = tid + k * SCAT_STRIDE;
            occ[e] = atomicAdd(&counts[dst[e]], 1);
        }
    }
}

// ---------------- scans (scan2 fused into scan3) ----------------
__global__ __launch_bounds__(256) void k_scan1(const int* __restrict__ counts,
                                               int* __restrict__ csum) {
    __shared__ int sd[256];
    int t = threadIdx.x;
    int base = blockIdx.x * SCAN_CH + t * 4;
    int s = 0;
#pragma unroll
    for (int u = 0; u < 4; ++u) {
        int i = base + u;
        if (i < NN) s += counts[i];
    }
    sd[t] = s;
    __syncthreads();
    for (int off = 128; off > 0; off >>= 1) {
        if (t < off) sd[t] += sd[t + off];
        __syncthreads();
    }
    if (t == 0) csum[blockIdx.x] = sd[0];
}

__global__ __launch_bounds__(256) void k_scan3(const int* __restrict__ counts,
                                               const int* __restrict__ csum,
                                               int* __restrict__ row_ptr) {
    __shared__ int sd[256];
    __shared__ int sbase;
    int t = threadIdx.x, b = blockIdx.x;
    if (t < 64) {
        int acc = 0;
        for (int i = t; i < b; i += 64) acc += csum[i];
#pragma unroll
        for (int m = 1; m < 64; m <<= 1) acc += __shfl_xor(acc, m);
        if (t == 0) sbase = acc;
    }
    int base = b * SCAN_CH + t * 4;
    int v[4];
    int s = 0;
#pragma unroll
    for (int u = 0; u < 4; ++u) {
        int i = base + u;
        v[u] = (i < NN) ? counts[i] : 0;
        s += v[u];
    }
    sd[t] = s;
    __syncthreads();
    for (int off = 1; off < 256; off <<= 1) {
        int x = (t >= off) ? sd[t - off] : 0;
        __syncthreads();
        sd[t] += x;
        __syncthreads();
    }
    int excl = (t == 0) ? 0 : sd[t - 1];
    int run = sbase + excl;
#pragma unroll
    for (int u = 0; u < 4; ++u) {
        int i = base + u;
        if (i < NN) row_ptr[i] = run;
        run += v[u];
    }
    if (b == 0 && t == 0) row_ptr[NN] = NE;
}

// shared GEMM epilogue: h (bf16, node-major [NN][128]) + attention logits
__device__ inline void gemm_epilogue(f32x4 acc[8], int row0, int w, int col, int kq,
                                     const float* __restrict__ atts,
                                     const float* __restrict__ attd,
                                     u16* __restrict__ hb,
                                     float* __restrict__ a_src,
                                     float* __restrict__ a_dst) {
    float as0[4], as1[4], ad0[4], ad1[4];
#pragma unroll
    for (int q = 0; q < 4; ++q) {
        as0[q] = atts[q * 32 + col];
        as1[q] = atts[q * 32 + 16 + col];
        ad0[q] = attd[q * 32 + col];
        ad1[q] = attd[q * 32 + 16 + col];
    }
#pragma unroll
    for (int r = 0; r < 4; ++r) {
        int node = row0 + w * 16 + kq * 4 + r;
        float ps[4], pd[4];
#pragma unroll
        for (int q = 0; q < 4; ++q) {
            float d0 = acc[2 * q][r], d1 = acc[2 * q + 1][r];
            ps[q] = d0 * as0[q] + d1 * as1[q];
            pd[q] = d0 * ad0[q] + d1 * ad1[q];
        }
#pragma unroll
        for (int off = 1; off < 16; off <<= 1) {
#pragma unroll
            for (int q = 0; q < 4; ++q) {
                ps[q] += __shfl_xor(ps[q], off);
                pd[q] += __shfl_xor(pd[q], off);
            }
        }
        if (node < NN) {
#pragma unroll
            for (int ct = 0; ct < 8; ++ct)
                hb[(size_t)node * 128 + ct * 16 + col] = (u16)bf16r(acc[ct][r]);
            if (col < 4) {
                float vs = col == 0 ? ps[0] : col == 1 ? ps[1] : col == 2 ? ps[2] : ps[3];
                float vd = col == 0 ? pd[0] : col == 1 ? pd[1] : col == 2 ? pd[2] : pd[3];
                a_src[node * 4 + col] = vs;
                a_dst[node * 4 + col] = vd;
            }
        }
    }
}

// ---------------- fused: persistent scatter | gemm1 -------------------------
__global__ __launch_bounds__(256) void k_sg(
    const float* __restrict__ x,
    const bf16x8* __restrict__ wpH, const bf16x8* __restrict__ wpL,
    const float* __restrict__ atts, const float* __restrict__ attd,
    u16* __restrict__ hb, float* __restrict__ a_src, float* __restrict__ a_dst,
    const int* __restrict__ src, const int* __restrict__ dst,
    const int* __restrict__ occ, const int* __restrict__ row_ptr,
    int* __restrict__ src_sorted) {
    const int idx = blockIdx.x;
    if (idx < SCAT_BLOCKS) {
        int tid = idx * 256 + threadIdx.x;
#pragma unroll
        for (int k = 0; k < 10; ++k) {
            int e = tid + k * SCAT_STRIDE;
            int d = dst[e];
            src_sorted[row_ptr[d] + occ[e]] = src[e];
        }
        return;
    }
    const int t = threadIdx.x;
    const int row0 = (idx - SCAT_BLOCKS) * 64;
    const int lane = t & 63;
    const int w = t >> 6;
    const int col = lane & 15, kq = lane >> 4;
    int node_a = row0 + w * 16 + col;
    if (node_a > NN - 1) node_a = NN - 1;
    const float* xrow = x + (size_t)node_a * 128 + kq * 8;
    float a[32];
#pragma unroll
    for (int kc = 0; kc < 4; ++kc) {
        *(float4*)&a[kc * 8 + 0] = *(const float4*)(xrow + kc * 32);
        *(float4*)&a[kc * 8 + 4] = *(const float4*)(xrow + kc * 32 + 4);
    }
    f32x4 acc[8];
#pragma unroll
    for (int ct = 0; ct < 8; ++ct) acc[ct] = (f32x4){0.f, 0.f, 0.f, 0.f};
#pragma unroll
    for (int kc = 0; kc < 4; ++kc) {
        u32 hh[4], ll[4];
        split_pack8(&a[kc * 8], hh, ll);
        bf16x8 ah = __builtin_bit_cast(bf16x8, (u32x4){hh[0], hh[1], hh[2], hh[3]});
        bf16x8 al = __builtin_bit_cast(bf16x8, (u32x4){ll[0], ll[1], ll[2], ll[3]});
#pragma unroll
        for (int ct = 0; ct < 8; ++ct) {
            bf16x8 bh = wpH[(kc * 8 + ct) * 64 + lane];
            bf16x8 bl = wpL[(kc * 8 + ct) * 64 + lane];
            acc[ct] = __builtin_amdgcn_mfma_f32_16x16x32_bf16(ah, bh, acc[ct], 0, 0, 0);
            acc[ct] = __builtin_amdgcn_mfma_f32_16x16x32_bf16(al, bh, acc[ct], 0, 0, 0);
            acc[ct] = __builtin_amdgcn_mfma_f32_16x16x32_bf16(ah, bl, acc[ct], 0, 0, 0);
        }
    }
    gemm_epilogue(acc, row0, w, col, kq, atts, attd, hb, a_src, a_dst);
}

// ---------------- GEMM layer 2: bf16 input (exact A), LDS-free --------------
__global__ __launch_bounds__(256) void k_gemm2(
    const u32* __restrict__ xb,   // [NN][64] bf16 pairs (ch 2j low, 2j+1 high)
    const bf16x8* __restrict__ wpH, const bf16x8* __restrict__ wpL,
    const float* __restrict__ atts, const float* __restrict__ attd,
    u16* __restrict__ hb, float* __restrict__ a_src, float* __restrict__ a_dst) {
    const int t = threadIdx.x;
    const int row0 = blockIdx.x * 64;
    const int lane = t & 63;
    const int w = t >> 6;
    const int col = lane & 15, kq = lane >> 4;
    int node_a = row0 + w * 16 + col;
    if (node_a > NN - 1) node_a = NN - 1;
    const u32* xrow = xb + (size_t)node_a * 64 + kq * 4;
    int4 aw[4];
#pragma unroll
    for (int kc = 0; kc < 4; ++kc) aw[kc] = *(const int4*)(xrow + kc * 16);
    f32x4 acc[8];
#pragma unroll
    for (int ct = 0; ct < 8; ++ct) acc[ct] = (f32x4){0.f, 0.f, 0.f, 0.f};
#pragma unroll
    for (int kc = 0; kc < 4; ++kc) {
        bf16x8 a = __builtin_bit_cast(bf16x8, aw[kc]);
#pragma unroll
        for (int ct = 0; ct < 8; ++ct) {
            bf16x8 bh = wpH[(kc * 8 + ct) * 64 + lane];
            bf16x8 bl = wpL[(kc * 8 + ct) * 64 + lane];
            acc[ct] = __builtin_amdgcn_mfma_f32_16x16x32_bf16(a, bh, acc[ct], 0, 0, 0);
            acc[ct] = __builtin_amdgcn_mfma_f32_16x16x32_bf16(a, bl, acc[ct], 0, 0, 0);
        }
    }
    gemm_epilogue(acc, row0, w, col, kq, atts, attd, hb, a_src, a_dst);
}

// ---------------- aggregation: r8 body, 256-thr blocks (dispatch test) ------
// 4 waves/block, 2 consecutive nodes per wave -> 12.5k blocks (4x fewer than
// r8's 50k). Body identical to the proven 88us version: per 16-edge chunk,
// all 16 hb loads in flight, then 16 broadcasts, then 32 FMAs.
__global__ __launch_bounds__(256, 4) void k_agg(
    const u32* __restrict__ hb,   // [NN][64] bf16 pairs
    const float* __restrict__ a_src, const float* __restrict__ a_dst,
    const int* __restrict__ row_ptr, const int* __restrict__ src_sorted,
    const float* __restrict__ bias,
    u32* __restrict__ x1b, float* __restrict__ outp, int layer) {
    const int lane = threadIdx.x & 63;
    const int node0 = blockIdx.x * 8 + (threadIdx.x >> 6) * 2;
    const int q = lane >> 4;
    const int es = lane & 15;
    const int hbase = lane & 48;
#pragma unroll
    for (int ni = 0; ni < 2; ++ni) {
        const int node = node0 + ni;
        if (node >= NN) continue;
        const int e0 = row_ptr[node], e1 = row_ptr[node + 1];
        const int emax = e1 - 1;
        const float advh = a_dst[node * 4 + q];
        float den = 0.f, a0a = 0.f, a0b = 0.f, a1a = 0.f, a1b = 0.f;
        if (e1 > e0) {
            int eidx = e0 + es;
            if (eidx > emax) eidx = emax;
            int sv = src_sorted[eidx];
            float av = a_src[sv * 4 + q];
            for (int ec = e0; ec < e1; ec += 16) {
                int cnt = e1 - ec;
                cnt = cnt < 16 ? cnt : 16;
                int eidxn = ec + 16 + es;
                if (eidxn > emax) eidxn = emax;
                int svn = src_sorted[eidxn];
                float avn = a_src[svn * 4 + q];
                float lk = av + advh;
                lk = lk > 0.f ? lk : 0.2f * lk;
                float ex = (es < cnt) ? __expf(lk - 8.f) : 0.f;
                den += ex;
                if (cnt == 16) {
                    u32 wv[16];
#pragma unroll
                    for (int u = 0; u < 16; ++u) {
                        int su = __builtin_amdgcn_readlane(sv, u);
                        wv[u] = hb[((size_t)su << 6) + lane];
                    }
                    float exu[16];
#pragma unroll
                    for (int u = 0; u < 16; ++u) exu[u] = __shfl(ex, hbase | u);
#pragma unroll
                    for (int u = 0; u < 16; ++u) {
                        float h0 = __uint_as_float(wv[u] << 16);
                        float h1 = __uint_as_float(wv[u] & 0xFFFF0000u);
                        if (u & 1) { a0b = fmaf(exu[u], h0, a0b); a1b = fmaf(exu[u], h1, a1b); }
                        else       { a0a = fmaf(exu[u], h0, a0a); a1a = fmaf(exu[u], h1, a1a); }
                    }
                } else {
                    for (int u0 = 0; u0 < cnt; u0 += 4) {
                        u32 wv[4];
                        float exu[4];
#pragma unroll
                        for (int j = 0; j < 4; ++j) {
                            int su = __builtin_amdgcn_readlane(sv, u0 + j);
                            wv[j] = hb[((size_t)su << 6) + lane];
                        }
#pragma unroll
                        for (int j = 0; j < 4; ++j) exu[j] = __shfl(ex, hbase | (u0 + j));
#pragma unroll
                        for (int j = 0; j < 4; ++j) {
                            float h0 = __uint_as_float(wv[j] << 16);
                            float h1 = __uint_as_float(wv[j] & 0xFFFF0000u);
                            if (j & 1) { a0b = fmaf(exu[j], h0, a0b); a1b = fmaf(exu[j], h1, a1b); }
                            else       { a0a = fmaf(exu[j], h0, a0a); a1a = fmaf(exu[j], h1, a1a); }
                        }
                    }
                }
                sv = svn;
                av = avn;
            }
        }
        float a0 = a0a + a0b, a1 = a1a + a1b;
#pragma unroll
        for (int m = 1; m < 16; m <<= 1) den += __shfl_xor(den, m);
        float inv = den > 0.f ? 1.f / den : 0.f;
        int c0 = lane * 2;
        float r0 = fmaxf(fmaf(a0, inv, bias[c0]), 0.f);
        float r1 = fmaxf(fmaf(a1, inv, bias[c0 + 1]), 0.f);
        if (layer == 1) {
            x1b[node * 64 + lane] = bf16r(r0) | (bf16r(r1) << 16);
        } else {
            u32 w1 = x1b[node * 64 + lane];
            float4 o;
            o.x = __uint_as_float(w1 << 16);          // x1[2l]
            o.y = r0;                                  // x2[2l]
            o.z = __uint_as_float(w1 & 0xFFFF0000u);  // x1[2l+1]
            o.w = r1;                                  // x2[2l+1]
            *(float4*)(outp + (size_t)node * 256 + lane * 4) = o;
        }
    }
}

// ---------------- launch ----------------

extern "C" void kernel_launch(void* const* d_in, const int* in_sizes, int n_in,
                              void* d_out, int out_size, void* d_ws, size_t ws_size,
                              hipStream_t stream) {
    const float* x   = (const float*)d_in[0];
    const int*   ei  = (const int*)d_in[1];
    const float* W1  = (const float*)d_in[2];
    const float* as1 = (const float*)d_in[3];
    const float* ad1 = (const float*)d_in[4];
    const float* b1  = (const float*)d_in[5];
    const float* W2  = (const float*)d_in[6];
    const float* as2 = (const float*)d_in[7];
    const float* ad2 = (const float*)d_in[8];
    const float* b2  = (const float*)d_in[9];
    float* out = (float*)d_out;
    const int* src = ei;
    const int* dst = ei + NE;

    char* w = (char*)d_ws;
    size_t off = 0;
    auto alloc = [&](size_t bytes) -> void* {
        void* p = w + off;
        off = (off + bytes + 255) & ~((size_t)255);
        return p;
    };
    u16* hb         = (u16*)alloc((size_t)NN * 128 * 2);   // h as bf16
    u32* x1b        = (u32*)alloc((size_t)NN * 64 * 4);    // x1 as bf16 pairs
    float* a_src    = (float*)alloc((size_t)NN * 4 * 4);
    float* a_dst    = (float*)alloc((size_t)NN * 4 * 4);
    int* counts     = (int*)alloc((size_t)NN * 4);
    int* row_ptr    = (int*)alloc((size_t)(NN + 1) * 4);
    int* csum       = (int*)alloc(4096);
    int* occ        = (int*)alloc((size_t)NE * 4);
    int* src_sorted = (int*)alloc((size_t)NE * 4);
    bf16x8* wpH1    = (bf16x8*)alloc(2048 * 16);
    bf16x8* wpL1    = (bf16x8*)alloc(2048 * 16);
    bf16x8* wpH2    = (bf16x8*)alloc(2048 * 16);
    bf16x8* wpL2    = (bf16x8*)alloc(2048 * 16);

    const int nch = (NN + SCAN_CH - 1) / SCAN_CH;  // 98

    (void)hipMemsetAsync(counts, 0, (size_t)NN * 4, stream);
    k_wh<<<WH_GRID, 256, 0, stream>>>(W1, wpH1, wpL1, W2, wpH2, wpL2,
                                      dst, counts, occ);
    k_scan1<<<nch, 256, 0, stream>>>(counts, csum);
    k_scan3<<<nch, 256, 0, stream>>>(counts, csum, row_ptr);
    k_sg<<<SG_GRID, 256, 0, stream>>>(x, wpH1, wpL1, as1, ad1, hb, a_src, a_dst,
                                      src, dst, occ, row_ptr, src_sorted);

    k_agg<<<AGG_GRID, 256, 0, stream>>>((const u32*)hb, a_src, a_dst, row_ptr,
                                        src_sorted, b1, x1b, out, 1);
    k_gemm2<<<(NN + 63) / 64, 256, 0, stream>>>(x1b, wpH2, wpL2, as2, ad2,
                                                hb, a_src, a_dst);
    k_agg<<<AGG_GRID, 256, 0, stream>>>((const u32*)hb, a_src, a_dst, row_ptr,
                                        src_sorted, b2, x1b, out, 2);
}